// Round 5
// baseline (323.774 us; speedup 1.0000x reference)
//
#include <hip/hip_runtime.h>

typedef unsigned int u32;
typedef unsigned short u16;
typedef __bf16 bf16x8 __attribute__((ext_vector_type(8)));
typedef float f32x4 __attribute__((ext_vector_type(4)));

#define HID 128

__device__ __forceinline__ u16 f2bf(float f) {
  u32 u = __float_as_uint(f);
  u32 r = u + 0x7FFFu + ((u >> 16) & 1u);
  return (u16)(r >> 16);
}
__device__ __forceinline__ float bflo(u32 a) { return __uint_as_float(a << 16); }
__device__ __forceinline__ float bfhi(u32 a) { return __uint_as_float(a & 0xFFFF0000u); }

// ---- CSR build ----------------------------------------------------------
__global__ void k_deg(const int* __restrict__ dst, int* __restrict__ deg,
                      int* __restrict__ rank, int E) {
  int e = blockIdx.x * blockDim.x + threadIdx.x;
  if (e < E) rank[e] = atomicAdd(&deg[dst[e]], 1);
}

// segment allocator: per-wave prefix sum of deg + one atomic per wave.
__global__ void k_alloc(const int* __restrict__ deg, int* __restrict__ rp,
                        int* __restrict__ total, int n) {
  int i = blockIdx.x * blockDim.x + threadIdx.x;
  int lane = threadIdx.x & 63;
  int d = (i < n) ? deg[i] : 0;
  int incl = d;
#pragma unroll
  for (int off = 1; off < 64; off <<= 1) {
    int t = __shfl_up(incl, off);
    if (lane >= off) incl += t;
  }
  int wtot = __shfl(incl, 63);
  int base = 0;
  if (lane == 63) base = atomicAdd(total, wtot);
  base = __shfl(base, 63);
  if (i < n) rp[i] = base + incl - d;
}

__global__ void k_scatter(const int* __restrict__ src, const int* __restrict__ dst,
                          const int* __restrict__ rp, const int* __restrict__ rank,
                          int* __restrict__ col, int E) {
  int e = blockIdx.x * blockDim.x + threadIdx.x;
  if (e < E) col[rp[dst[e]] + rank[e]] = src[e];
}

// ---- prep: all weight packs + feature fp32->bf16 convert, one launch ----
// P[nt][kt][lane][j] = W[(kt*32 + (lane>>4)*8 + j)*N + nt*16 + (lane&15)]
__device__ __forceinline__ void pack_one(const float* __restrict__ W,
                                         u16* __restrict__ P, int N, int t) {
  int lane = t & 63;
  int kt = (t >> 6) & 3;
  int nt = t >> 8;
  int colc = nt * 16 + (lane & 15);
  int krow = kt * 32 + (lane >> 4) * 8;
  u16* d = P + (size_t)t * 8;
#pragma unroll
  for (int j = 0; j < 8; ++j) d[j] = f2bf(W[(krow + j) * N + colc]);
}

__global__ void k_prep(const float* __restrict__ x, u32* __restrict__ xb, int n4,
                       const float* __restrict__ W1l, const float* __restrict__ W1r,
                       const float* __restrict__ W2l, const float* __restrict__ W2r,
                       const float* __restrict__ W3l, const float* __restrict__ W3r,
                       u16* __restrict__ P1l, u16* __restrict__ P1r,
                       u16* __restrict__ P2l, u16* __restrict__ P2r,
                       u16* __restrict__ P3l, u16* __restrict__ P3r) {
  int t = blockIdx.x * blockDim.x + threadIdx.x;
  if (t < 10240) {
    if (t < 2048) pack_one(W1l, P1l, 128, t);
    else if (t < 4096) pack_one(W1r, P1r, 128, t - 2048);
    else if (t < 6144) pack_one(W2l, P2l, 128, t - 4096);
    else if (t < 8192) pack_one(W2r, P2r, 128, t - 6144);
    else if (t < 9216) pack_one(W3l, P3l, 64, t - 8192);
    else pack_one(W3r, P3r, 64, t - 9216);
    return;
  }
  int c = t - 10240;
  if (c < n4) {
    f32x4 v = ((const f32x4*)x)[c];
    xb[c * 2] = (u32)f2bf(v[0]) | ((u32)f2bf(v[1]) << 16);
    xb[c * 2 + 1] = (u32)f2bf(v[2]) | ((u32)f2bf(v[3]) << 16);
  }
}

// ---- fused layer: aggregate-into-LDS + MFMA gemm, no global agg buffer --
// block = 4 waves x 16 nodes. Wave w owns rows [blk*64 + w*16, +16):
//   phase 1: mean-aggregate each row's neighbors into wave-local LDS (bf16 pairs)
//   phase 2: out = aggLDS@Wl + feat@Wr + b (+relu), MFMA 16x16x32 bf16
// No __syncthreads needed: LDS is wave-private, so OOB waves may return early.
template <int NT, bool RELU, bool OUTF32>
__global__ void k_layer(const u16* __restrict__ feat, const int* __restrict__ rp,
                        const int* __restrict__ deg, const int* __restrict__ col,
                        const u16* __restrict__ Pl, const u16* __restrict__ Pr,
                        const float* __restrict__ bias, void* __restrict__ outp,
                        int n) {
  __shared__ u32 sm[4][16][68];  // stride 68 u32 (272B) breaks bank alignment
  int wave = threadIdx.x >> 6;
  int lane = threadIdx.x & 63;
  int g0 = blockIdx.x * 64 + wave * 16;
  if (g0 >= n) return;

  // ---- phase 1: aggregate 16 rows into LDS ----
  const u32* fb = (const u32*)feat + lane;  // row stride 64 u32
  for (int r = 0; r < 16; ++r) {
    int g = g0 + r;
    if (g >= n) break;
    int beg = rp[g];
    int d = deg[g];
    int end = beg + d;
    float s0 = 0.f, s1 = 0.f, t0 = 0.f, t1 = 0.f;
    float u0 = 0.f, u1 = 0.f, v0 = 0.f, v1 = 0.f;
    int e = beg;
    for (; e + 4 <= end; e += 4) {
      int j0 = col[e], j1 = col[e + 1], j2 = col[e + 2], j3 = col[e + 3];
      u32 a = fb[(size_t)j0 * 64];
      u32 b = fb[(size_t)j1 * 64];
      u32 c = fb[(size_t)j2 * 64];
      u32 dd = fb[(size_t)j3 * 64];
      s0 += bflo(a); s1 += bfhi(a);
      t0 += bflo(b); t1 += bfhi(b);
      u0 += bflo(c); u1 += bfhi(c);
      v0 += bflo(dd); v1 += bfhi(dd);
    }
    for (; e < end; ++e) {
      u32 a = fb[(size_t)col[e] * 64];
      s0 += bflo(a); s1 += bfhi(a);
    }
    float a0 = (s0 + t0) + (u0 + v0);
    float a1 = (s1 + t1) + (u1 + v1);
    float inv = 1.0f / (float)max(d, 1);
    a0 *= inv;
    a1 *= inv;
    sm[wave][r][lane] = (u32)f2bf(a0) | ((u32)f2bf(a1) << 16);
  }

  // ---- phase 2: MFMA ----
  int rl = lane & 15;
  int kg = lane >> 4;
  f32x4 acc[NT];
#pragma unroll
  for (int nt = 0; nt < NT; ++nt) acc[nt] = 0.f;

  int grow = min(g0 + rl, n - 1);
  const u16* ph = feat + (size_t)grow * HID + kg * 8;

#pragma unroll
  for (int kt = 0; kt < 4; ++kt) {
    bf16x8 aa = *(const bf16x8*)&sm[wave][rl][kt * 16 + kg * 4];
#pragma unroll
    for (int nt = 0; nt < NT; ++nt) {
      bf16x8 bf = *(const bf16x8*)(Pl + ((size_t)(nt * 4 + kt) * 64 + lane) * 8);
      acc[nt] = __builtin_amdgcn_mfma_f32_16x16x32_bf16(aa, bf, acc[nt], 0, 0, 0);
    }
  }
#pragma unroll
  for (int kt = 0; kt < 4; ++kt) {
    bf16x8 ah = *(const bf16x8*)(ph + kt * 32);
#pragma unroll
    for (int nt = 0; nt < NT; ++nt) {
      bf16x8 bf = *(const bf16x8*)(Pr + ((size_t)(nt * 4 + kt) * 64 + lane) * 8);
      acc[nt] = __builtin_amdgcn_mfma_f32_16x16x32_bf16(ah, bf, acc[nt], 0, 0, 0);
    }
  }

  const int N = NT * 16;
  int rq = lane >> 4;
#pragma unroll
  for (int nt = 0; nt < NT; ++nt) {
    float bv = bias[nt * 16 + rl];
#pragma unroll
    for (int j = 0; j < 4; ++j) {
      int r = g0 + rq * 4 + j;
      if (r >= n) continue;
      float v = acc[nt][j] + bv;
      if (RELU) v = fmaxf(v, 0.f);
      if (OUTF32)
        ((float*)outp)[(size_t)r * N + nt * 16 + rl] = v;
      else
        ((u16*)outp)[(size_t)r * N + nt * 16 + rl] = f2bf(v);
    }
  }
}

extern "C" void kernel_launch(void* const* d_in, const int* in_sizes, int n_in,
                              void* d_out, int out_size, void* d_ws, size_t ws_size,
                              hipStream_t stream) {
  const float* x = (const float*)d_in[0];
  const int* ei = (const int*)d_in[1];
  const float* W1l = (const float*)d_in[2];
  const float* W1r = (const float*)d_in[3];
  const float* b1 = (const float*)d_in[4];
  const float* W2l = (const float*)d_in[5];
  const float* W2r = (const float*)d_in[6];
  const float* b2 = (const float*)d_in[7];
  const float* W3l = (const float*)d_in[8];
  const float* W3r = (const float*)d_in[9];
  const float* b3 = (const float*)d_in[10];

  const int E = in_sizes[1] / 2;
  const int N = in_sizes[0] / HID;
  const int* esrc = ei;
  const int* edst = ei + E;

  char* wp = (char*)d_ws;
  auto alloc = [&](size_t b) {
    char* p = wp;
    wp += (b + 255) & ~(size_t)255;
    return p;
  };
  int* deg = (int*)alloc((size_t)(N + 1) * 4);  // deg[N] = total counter
  int* rp = (int*)alloc((size_t)N * 4);
  int* rank = (int*)alloc((size_t)E * 4);
  int* col = (int*)alloc((size_t)E * 4);
  u16* featA = (u16*)alloc((size_t)N * HID * 2);
  u16* featB = (u16*)alloc((size_t)N * HID * 2);
  u16* P1l = (u16*)alloc(8 * 4 * 64 * 8 * 2);
  u16* P1r = (u16*)alloc(8 * 4 * 64 * 8 * 2);
  u16* P2l = (u16*)alloc(8 * 4 * 64 * 8 * 2);
  u16* P2r = (u16*)alloc(8 * 4 * 64 * 8 * 2);
  u16* P3l = (u16*)alloc(4 * 4 * 64 * 8 * 2);
  u16* P3r = (u16*)alloc(4 * 4 * 64 * 8 * 2);

  hipMemsetAsync(deg, 0, (size_t)(N + 1) * 4, stream);

  int eb = (E + 255) / 256;
  k_deg<<<eb, 256, 0, stream>>>(edst, deg, rank, E);
  k_alloc<<<(N + 255) / 256, 256, 0, stream>>>(deg, rp, deg + N, N);
  k_scatter<<<eb, 256, 0, stream>>>(esrc, edst, rp, rank, col, E);

  int n4 = N * (HID / 4);
  k_prep<<<(10240 + n4 + 255) / 256, 256, 0, stream>>>(
      x, (u32*)featA, n4, W1l, W1r, W2l, W2r, W3l, W3r, P1l, P1r, P2l, P2r, P3l, P3r);

  int lb = (N + 63) / 64;  // one block (4 waves x 16 rows) per 64 nodes

  // layer 1: featA(x) -> featB
  k_layer<8, true, false><<<lb, 256, 0, stream>>>(featA, rp, deg, col, P1l, P1r, b1, featB, N);
  // layer 2: featB -> featA
  k_layer<8, true, false><<<lb, 256, 0, stream>>>(featB, rp, deg, col, P2l, P2r, b2, featA, N);
  // layer 3: featA -> d_out (fp32, no relu)
  k_layer<4, false, true><<<lb, 256, 0, stream>>>(featA, rp, deg, col, P3l, P3r, b3, (float*)d_out, N);
}

// Round 6
// 266.084 us; speedup vs baseline: 1.2168x; 1.2168x over previous
//
#include <hip/hip_runtime.h>

typedef unsigned int u32;
typedef unsigned short u16;
typedef __bf16 bf16x8 __attribute__((ext_vector_type(8)));
typedef float f32x4 __attribute__((ext_vector_type(4)));

#define HID 128

__device__ __forceinline__ u16 f2bf(float f) {
  u32 u = __float_as_uint(f);
  u32 r = u + 0x7FFFu + ((u >> 16) & 1u);
  return (u16)(r >> 16);
}
__device__ __forceinline__ float bflo(u32 a) { return __uint_as_float(a << 16); }
__device__ __forceinline__ float bfhi(u32 a) { return __uint_as_float(a & 0xFFFF0000u); }

// ---- CSR build ----------------------------------------------------------
__global__ void k_deg(const int* __restrict__ dst, int* __restrict__ deg,
                      int* __restrict__ rank, int E) {
  int e = blockIdx.x * blockDim.x + threadIdx.x;
  if (e < E) rank[e] = atomicAdd(&deg[dst[e]], 1);
}

// segment allocator: per-wave prefix sum of deg + one atomic per wave.
__global__ void k_alloc(const int* __restrict__ deg, int* __restrict__ rp,
                        int* __restrict__ total, int n) {
  int i = blockIdx.x * blockDim.x + threadIdx.x;
  int lane = threadIdx.x & 63;
  int d = (i < n) ? deg[i] : 0;
  int incl = d;
#pragma unroll
  for (int off = 1; off < 64; off <<= 1) {
    int t = __shfl_up(incl, off);
    if (lane >= off) incl += t;
  }
  int wtot = __shfl(incl, 63);
  int base = 0;
  if (lane == 63) base = atomicAdd(total, wtot);
  base = __shfl(base, 63);
  if (i < n) rp[i] = base + incl - d;
}

// ---- merged scatter + weight-pack + feature-convert ---------------------
// P[nt][kt][lane][j] = W[(kt*32 + (lane>>4)*8 + j)*N + nt*16 + (lane&15)]
__device__ __forceinline__ void pack_one(const float* __restrict__ W,
                                         u16* __restrict__ P, int N, int t) {
  int lane = t & 63;
  int kt = (t >> 6) & 3;
  int nt = t >> 8;
  int colc = nt * 16 + (lane & 15);
  int krow = kt * 32 + (lane >> 4) * 8;
  u16* d = P + (size_t)t * 8;
#pragma unroll
  for (int j = 0; j < 8; ++j) d[j] = f2bf(W[(krow + j) * N + colc]);
}

__global__ void k_sp(const int* __restrict__ src, const int* __restrict__ dst,
                     const int* __restrict__ rp, const int* __restrict__ rank,
                     int* __restrict__ col, int E,
                     const float* __restrict__ x, u32* __restrict__ xb, int n4,
                     const float* __restrict__ W1l, const float* __restrict__ W1r,
                     const float* __restrict__ W2l, const float* __restrict__ W2r,
                     const float* __restrict__ W3l, const float* __restrict__ W3r,
                     u16* __restrict__ P1l, u16* __restrict__ P1r,
                     u16* __restrict__ P2l, u16* __restrict__ P2r,
                     u16* __restrict__ P3l, u16* __restrict__ P3r) {
  int t = blockIdx.x * blockDim.x + threadIdx.x;
  if (t < E) col[rp[dst[t]] + rank[t]] = src[t];
  if (t < 10240) {
    if (t < 2048) pack_one(W1l, P1l, 128, t);
    else if (t < 4096) pack_one(W1r, P1r, 128, t - 2048);
    else if (t < 6144) pack_one(W2l, P2l, 128, t - 4096);
    else if (t < 8192) pack_one(W2r, P2r, 128, t - 6144);
    else if (t < 9216) pack_one(W3l, P3l, 64, t - 8192);
    else pack_one(W3r, P3r, 64, t - 9216);
    return;
  }
  int c = t - 10240;
  if (c < n4) {
    f32x4 v = ((const f32x4*)x)[c];
    xb[c * 2] = (u32)f2bf(v[0]) | ((u32)f2bf(v[1]) << 16);
    xb[c * 2 + 1] = (u32)f2bf(v[2]) | ((u32)f2bf(v[3]) << 16);
  }
}

// ---- mean aggregation: one wave per node, 8-deep gather pipeline --------
__global__ void k_agg(const u16* __restrict__ feat, const int* __restrict__ rp,
                      const int* __restrict__ deg, const int* __restrict__ col,
                      u16* __restrict__ agg, int n) {
  int w = (blockIdx.x * blockDim.x + threadIdx.x) >> 6;
  int lane = threadIdx.x & 63;
  if (w >= n) return;
  int beg = rp[w];
  int d = deg[w];
  int end = beg + d;
  const u32* fb = (const u32*)feat + lane;  // row stride 64 u32
  float s0 = 0.f, s1 = 0.f, t0 = 0.f, t1 = 0.f;
  float u0 = 0.f, u1 = 0.f, v0 = 0.f, v1 = 0.f;
  int e = beg;
  // 8 independent loads in flight per iteration
  for (; e + 8 <= end; e += 8) {
    int j0 = col[e],     j1 = col[e + 1], j2 = col[e + 2], j3 = col[e + 3];
    int j4 = col[e + 4], j5 = col[e + 5], j6 = col[e + 6], j7 = col[e + 7];
    u32 x0 = fb[(size_t)j0 * 64];
    u32 x1 = fb[(size_t)j1 * 64];
    u32 x2 = fb[(size_t)j2 * 64];
    u32 x3 = fb[(size_t)j3 * 64];
    u32 x4 = fb[(size_t)j4 * 64];
    u32 x5 = fb[(size_t)j5 * 64];
    u32 x6 = fb[(size_t)j6 * 64];
    u32 x7 = fb[(size_t)j7 * 64];
    s0 += bflo(x0); s1 += bfhi(x0);
    t0 += bflo(x1); t1 += bfhi(x1);
    u0 += bflo(x2); u1 += bfhi(x2);
    v0 += bflo(x3); v1 += bfhi(x3);
    s0 += bflo(x4); s1 += bfhi(x4);
    t0 += bflo(x5); t1 += bfhi(x5);
    u0 += bflo(x6); u1 += bfhi(x6);
    v0 += bflo(x7); v1 += bfhi(x7);
  }
  for (; e + 4 <= end; e += 4) {
    int j0 = col[e], j1 = col[e + 1], j2 = col[e + 2], j3 = col[e + 3];
    u32 x0 = fb[(size_t)j0 * 64];
    u32 x1 = fb[(size_t)j1 * 64];
    u32 x2 = fb[(size_t)j2 * 64];
    u32 x3 = fb[(size_t)j3 * 64];
    s0 += bflo(x0); s1 += bfhi(x0);
    t0 += bflo(x1); t1 += bfhi(x1);
    u0 += bflo(x2); u1 += bfhi(x2);
    v0 += bflo(x3); v1 += bfhi(x3);
  }
  for (; e < end; ++e) {
    u32 x0 = fb[(size_t)col[e] * 64];
    s0 += bflo(x0); s1 += bfhi(x0);
  }
  float a0 = (s0 + t0) + (u0 + v0);
  float a1 = (s1 + t1) + (u1 + v1);
  float inv = 1.0f / (float)max(d, 1);
  a0 *= inv;
  a1 *= inv;
  *(u32*)(agg + (size_t)w * HID + lane * 2) = (u32)f2bf(a0) | ((u32)f2bf(a1) << 16);
}

// ---- fused GEMM: out = agg@Wl + h@Wr + b (+relu), MFMA 16x16x32 bf16 ----
// one wave per MR 16-row tiles, NT 16-col tiles (N = NT*16)
template <int NT, int MR, bool RELU, bool OUTF32>
__global__ void k_gemm(const u16* __restrict__ Aagg, const u16* __restrict__ Ah,
                       const u16* __restrict__ Pl, const u16* __restrict__ Pr,
                       const float* __restrict__ bias, void* __restrict__ outp,
                       int mtiles, int n) {
  int wv = (blockIdx.x * blockDim.x + threadIdx.x) >> 6;
  int lane = threadIdx.x & 63;
  int tile0 = wv * MR;
  if (tile0 >= mtiles) return;

  f32x4 acc[MR][NT];
#pragma unroll
  for (int mr = 0; mr < MR; ++mr)
#pragma unroll
    for (int nt = 0; nt < NT; ++nt) acc[mr][nt] = 0.f;

  int rl = lane & 15;
  int kg = lane >> 4;
  int tm[MR];
  const u16 *pa[MR], *ph[MR];
#pragma unroll
  for (int mr = 0; mr < MR; ++mr) {
    tm[mr] = min(tile0 + mr, mtiles - 1);
    int row = tm[mr] * 16 + rl;
    pa[mr] = Aagg + (size_t)row * HID + kg * 8;
    ph[mr] = Ah + (size_t)row * HID + kg * 8;
  }

#pragma unroll
  for (int kt = 0; kt < 4; ++kt) {
    bf16x8 af[MR];
#pragma unroll
    for (int mr = 0; mr < MR; ++mr) af[mr] = *(const bf16x8*)(pa[mr] + kt * 32);
#pragma unroll
    for (int nt = 0; nt < NT; ++nt) {
      bf16x8 bf = *(const bf16x8*)(Pl + ((size_t)(nt * 4 + kt) * 64 + lane) * 8);
#pragma unroll
      for (int mr = 0; mr < MR; ++mr)
        acc[mr][nt] = __builtin_amdgcn_mfma_f32_16x16x32_bf16(af[mr], bf, acc[mr][nt], 0, 0, 0);
    }
  }
#pragma unroll
  for (int kt = 0; kt < 4; ++kt) {
    bf16x8 af[MR];
#pragma unroll
    for (int mr = 0; mr < MR; ++mr) af[mr] = *(const bf16x8*)(ph[mr] + kt * 32);
#pragma unroll
    for (int nt = 0; nt < NT; ++nt) {
      bf16x8 bf = *(const bf16x8*)(Pr + ((size_t)(nt * 4 + kt) * 64 + lane) * 8);
#pragma unroll
      for (int mr = 0; mr < MR; ++mr)
        acc[mr][nt] = __builtin_amdgcn_mfma_f32_16x16x32_bf16(af[mr], bf, acc[mr][nt], 0, 0, 0);
    }
  }

  const int N = NT * 16;
  int rq = lane >> 4;
#pragma unroll
  for (int mr = 0; mr < MR; ++mr) {
#pragma unroll
    for (int nt = 0; nt < NT; ++nt) {
      float bv = bias[nt * 16 + rl];
#pragma unroll
      for (int j = 0; j < 4; ++j) {
        float v = acc[mr][nt][j] + bv;
        if (RELU) v = fmaxf(v, 0.f);
        int r = tm[mr] * 16 + rq * 4 + j;
        if (OUTF32)
          ((float*)outp)[(size_t)r * N + nt * 16 + rl] = v;
        else
          ((u16*)outp)[(size_t)r * N + nt * 16 + rl] = f2bf(v);
      }
    }
  }
}

extern "C" void kernel_launch(void* const* d_in, const int* in_sizes, int n_in,
                              void* d_out, int out_size, void* d_ws, size_t ws_size,
                              hipStream_t stream) {
  const float* x = (const float*)d_in[0];
  const int* ei = (const int*)d_in[1];
  const float* W1l = (const float*)d_in[2];
  const float* W1r = (const float*)d_in[3];
  const float* b1 = (const float*)d_in[4];
  const float* W2l = (const float*)d_in[5];
  const float* W2r = (const float*)d_in[6];
  const float* b2 = (const float*)d_in[7];
  const float* W3l = (const float*)d_in[8];
  const float* W3r = (const float*)d_in[9];
  const float* b3 = (const float*)d_in[10];

  const int E = in_sizes[1] / 2;
  const int N = in_sizes[0] / HID;
  const int* esrc = ei;
  const int* edst = ei + E;

  char* wp = (char*)d_ws;
  auto alloc = [&](size_t b) {
    char* p = wp;
    wp += (b + 255) & ~(size_t)255;
    return p;
  };
  int* deg = (int*)alloc((size_t)(N + 1) * 4);  // deg[N] = total counter
  int* rp = (int*)alloc((size_t)N * 4);
  int* rank = (int*)alloc((size_t)E * 4);
  int* col = (int*)alloc((size_t)E * 4);
  u16* featA = (u16*)alloc((size_t)N * HID * 2);
  u16* featB = (u16*)alloc((size_t)N * HID * 2);
  u16* aggb = (u16*)alloc((size_t)N * HID * 2);
  u16* P1l = (u16*)alloc(8 * 4 * 64 * 8 * 2);
  u16* P1r = (u16*)alloc(8 * 4 * 64 * 8 * 2);
  u16* P2l = (u16*)alloc(8 * 4 * 64 * 8 * 2);
  u16* P2r = (u16*)alloc(8 * 4 * 64 * 8 * 2);
  u16* P3l = (u16*)alloc(4 * 4 * 64 * 8 * 2);
  u16* P3r = (u16*)alloc(4 * 4 * 64 * 8 * 2);

  hipMemsetAsync(deg, 0, (size_t)(N + 1) * 4, stream);

  int eb = (E + 255) / 256;
  k_deg<<<eb, 256, 0, stream>>>(edst, deg, rank, E);
  k_alloc<<<(N + 255) / 256, 256, 0, stream>>>(deg, rp, deg + N, N);

  int n4 = N * (HID / 4);
  int spn = 10240 + n4;
  if (E > spn) spn = E;
  k_sp<<<(spn + 255) / 256, 256, 0, stream>>>(
      esrc, edst, rp, rank, col, E, x, (u32*)featA, n4,
      W1l, W1r, W2l, W2r, W3l, W3r, P1l, P1r, P2l, P2r, P3l, P3r);

  int ab = (N * 64 + 255) / 256;  // one wave per node
  int mtiles = N / 16;
  int gwaves = (mtiles + 1) / 2;  // MR=2
  int gb = (gwaves * 64 + 255) / 256;

  // layer 1: featA(x) -> featB
  k_agg<<<ab, 256, 0, stream>>>(featA, rp, deg, col, aggb, N);
  k_gemm<8, 2, true, false><<<gb, 256, 0, stream>>>(aggb, featA, P1l, P1r, b1, featB, mtiles, N);
  // layer 2: featB -> featA
  k_agg<<<ab, 256, 0, stream>>>(featB, rp, deg, col, aggb, N);
  k_gemm<8, 2, true, false><<<gb, 256, 0, stream>>>(aggb, featB, P2l, P2r, b2, featA, mtiles, N);
  // layer 3: featA -> d_out (fp32, no relu)
  k_agg<<<ab, 256, 0, stream>>>(featA, rp, deg, col, aggb, N);
  k_gemm<4, 2, false, true><<<gb, 256, 0, stream>>>(aggb, featA, P3l, P3r, b3, (float*)d_out, mtiles, N);
}